// Round 17
// baseline (266.679 us; speedup 1.0000x reference)
//
#include <hip/hip_runtime.h>
#include <math.h>

#define N_SP 3136
#define BN_EPS 1e-5f

typedef __attribute__((ext_vector_type(8))) short short8;
typedef __attribute__((ext_vector_type(4))) float f32x4;

// ws layout (float elements)
#define K_SZ    (16*384*N_SP)            // kq packed u32 (k, bf16 hi|lo<<16)
#define KVP_OFF (K_SZ)
#define KVP_SZ  (16*6*7*64*80)           // per-chunk partials [d][80]
#define KVT_OFF (KVP_OFF + KVP_SZ)       // kvt bf16 hi/lo planes [bh][e:80][d:64]
#define KVT_FSZ (2*96*80*64/2)           // 491,520 floats
#define WH_OFF  (KVT_OFF + KVT_FSZ)      // wfrag hi/lo ushort planes
#define WSPLIT_N (2*384*192)
#define WF_G    (384*192)
#define PWS_OFF (WH_OFF + WSPLIT_N)
#define PSH_OFF (PWS_OFF + 384*9)
#define QSC_OFF (PSH_OFF + 384)
#define QSH_OFF (QSC_OFF + 384)

// both-sides LDS swizzle for B tiles
#define FSWZ(n) ((((n) >> 1) ^ ((n) >> 2)) & 7)

__device__ __forceinline__ void bsplit(float f, ushort& h, ushort& l) {
    uint u = __float_as_uint(f);
    uint hr = (u + 0x7FFFu + ((u >> 16) & 1u)) >> 16;
    h = (ushort)hr;
    float fh = __uint_as_float(hr << 16);
    float fl = f - fh;
    uint v = __float_as_uint(fl);
    l = (ushort)((v + 0x7FFFu + ((v >> 16) & 1u)) >> 16);
}

// ---------------- P0: qk_w -> fragment-layout bf16 hi/lo; pe weight/BN prescale; q BN tables.
__global__ __launch_bounds__(256) void p0_prep(
    const float* __restrict__ qk_w, const float* __restrict__ pe_w,
    const float* __restrict__ qk_gamma, const float* __restrict__ qk_beta,
    const float* __restrict__ qk_mean, const float* __restrict__ qk_var,
    const float* __restrict__ pgamma, const float* __restrict__ pbeta,
    const float* __restrict__ pmean, const float* __restrict__ pvar,
    ushort* __restrict__ wfh, ushort* __restrict__ wfl,
    float* __restrict__ pwsc, float* __restrict__ psh,
    float* __restrict__ qsc, float* __restrict__ qsh)
{
    int idx = blockIdx.x * 256 + threadIdx.x;
    if (idx < WSPLIT_N) {
        int g = (idx >= WF_G) ? 1 : 0;
        int rem = idx - g * WF_G;
        int row = rem / 192, k = rem % 192;
        ushort h, l;
        bsplit(qk_w[idx], h, l);
        int dst = g * WF_G + ((row >> 4) * 24 + (k >> 3)) * 128 + (row & 15) * 8 + (k & 7);
        wfh[dst] = h;
        wfl[dst] = l;
    }
    if (idx < 384) {
        float sc = pgamma[idx] / sqrtf(pvar[idx] + BN_EPS);
        psh[idx] = pbeta[idx] - pmean[idx] * sc;
        #pragma unroll
        for (int q = 0; q < 9; ++q) pwsc[idx * 9 + q] = pe_w[idx * 9 + q] * sc;
        float qs = qk_gamma[idx] / sqrtf(qk_var[idx] + BN_EPS);
        qsc[idx] = qs;
        qsh[idx] = qk_beta[idx] - qk_mean[idx] * qs;
    }
}

// ---------------- K1: k-only GEMM (g=1). Block = 192 rows x 64 n; A frag-direct (unchanged).
__global__ __launch_bounds__(256, 4) void k1_k_mfma(
    const float* __restrict__ x, const ushort* __restrict__ wfh, const ushort* __restrict__ wfl,
    const float* __restrict__ gamma, const float* __restrict__ beta,
    const float* __restrict__ mean, const float* __restrict__ var,
    uint* __restrict__ kq)
{
    __shared__ __align__(16) ushort Bh[4096];
    __shared__ __align__(16) ushort Bl[4096];
    __shared__ float scs[192], shs[192];

    const int bx = blockIdx.x;           // 49 n-tiles
    const int by = blockIdx.y;           // 2 row-halves
    const int b = blockIdx.z;            // 16
    const int t = threadIdx.x;
    const int lane = t & 63, wv = t >> 6;
    const int lg = lane >> 4, l15 = lane & 15;

    f32x4 acc[3][4];
    #pragma unroll
    for (int mf = 0; mf < 3; ++mf)
        #pragma unroll
        for (int nf = 0; nf < 4; ++nf)
            acc[mf][nf] = (f32x4){0.f, 0.f, 0.f, 0.f};

    const float* xg = x + (size_t)(b * 384 + 192) * N_SP + bx * 64;   // g=1 rows
    const ushort* wfbh = wfh + WF_G;
    const ushort* wfbl = wfl + WF_G;

    for (int i = t; i < 192; i += 256) {
        int ch = 384 + by * 192 + i;
        float sc = gamma[ch] / sqrtf(var[ch] + BN_EPS);
        scs[i] = sc;
        shs[i] = beta[ch] - mean[ch] * sc;
    }

    for (int kt = 0; kt < 3; ++kt) {
        #pragma unroll
        for (int li = 0; li < 2; ++li) {
            int idx = li * 256 + t;
            int kp = idx >> 4;
            int nq = idx & 15;
            int k0 = kp * 2;
            const float* px = xg + (size_t)(kt * 64 + k0) * N_SP + nq * 4;
            float4 v0 = *(const float4*)px;
            float4 v1 = *(const float4*)(px + N_SP);
            ushort h0[4], l0[4], h1[4], l1[4];
            float a0[4] = {v0.x, v0.y, v0.z, v0.w};
            float a1[4] = {v1.x, v1.y, v1.z, v1.w};
            #pragma unroll
            for (int i2 = 0; i2 < 4; ++i2) { bsplit(a0[i2], h0[i2], l0[i2]); bsplit(a1[i2], h1[i2], l1[i2]); }
            int kb = k0 >> 3, ks = kp & 3;
            #pragma unroll
            for (int i2 = 0; i2 < 4; ++i2) {
                int n = nq * 4 + i2;
                int chunk = n * 8 + (kb ^ FSWZ(n));
                ((uint*)Bh)[chunk * 4 + ks] = (uint)h0[i2] | ((uint)h1[i2] << 16);
                ((uint*)Bl)[chunk * 4 + ks] = (uint)l0[i2] | ((uint)l1[i2] << 16);
            }
        }
        __syncthreads();
        #pragma unroll
        for (int s = 0; s < 2; ++s) {
            int kbq = s * 4 + lg;
            int kglob = kt * 8 + kbq;
            short8 bh[4], bl[4];
            #pragma unroll
            for (int nf = 0; nf < 4; ++nf) {
                int n = nf * 16 + l15;
                int chunk = n * 8 + (kbq ^ FSWZ(n));
                bh[nf] = *(const short8*)&Bh[chunk * 8];
                bl[nf] = *(const short8*)&Bl[chunk * 8];
            }
            #pragma unroll
            for (int mf = 0; mf < 3; ++mf) {
                int rb = by * 12 + wv * 3 + mf;
                int off = (rb * 24 + kglob) * 128 + l15 * 8;
                short8 ah = *(const short8*)&wfbh[off];
                short8 al = *(const short8*)&wfbl[off];
                #pragma unroll
                for (int nf = 0; nf < 4; ++nf) {
                    acc[mf][nf] = __builtin_amdgcn_mfma_f32_16x16x32_bf16(ah, bh[nf], acc[mf][nf], 0, 0, 0);
                    acc[mf][nf] = __builtin_amdgcn_mfma_f32_16x16x32_bf16(ah, bl[nf], acc[mf][nf], 0, 0, 0);
                    acc[mf][nf] = __builtin_amdgcn_mfma_f32_16x16x32_bf16(al, bh[nf], acc[mf][nf], 0, 0, 0);
                }
            }
        }
        __syncthreads();
    }

    size_t obase = ((size_t)b * 384 + by * 192) * N_SP + bx * 64;
    #pragma unroll
    for (int mf = 0; mf < 3; ++mf)
        #pragma unroll
        for (int nf = 0; nf < 4; ++nf) {
            #pragma unroll
            for (int r = 0; r < 4; ++r) {
                int lrow = wv * 48 + mf * 16 + lg * 4 + r;
                float v = acc[mf][nf][r] * scs[lrow] + shs[lrow];
                v = v > 0.f ? v + 1.f : __expf(v);
                ushort hh, ll;
                bsplit(v, hh, ll);
                kq[obase + (size_t)lrow * N_SP + nf * 16 + l15] = (uint)hh | ((uint)ll << 16);
            }
        }
}

// ---------------- K2: kv + ksum via MFMA (unchanged).
__global__ __launch_bounds__(256) void k2_kv_mfma(
    const float* __restrict__ x, const uint* __restrict__ kq,
    float* __restrict__ kv_part)
{
    __shared__ __align__(16) ushort Kh[4096], Kl[4096];
    __shared__ __align__(16) ushort Vh[5120], Vl[5120];

    const int chunk = blockIdx.x;      // 7
    const int h = blockIdx.y, b = blockIdx.z;
    const int t = threadIdx.x;
    const int lane = t & 63, wv = t >> 6;
    const int lg = lane >> 4, l15 = lane & 15;

    const uint* kp  = kq + (size_t)(b*384 + h*64) * N_SP;
    const float* vp = x  + (size_t)(b*384 + h*64) * N_SP;

    #pragma unroll
    for (int li = 0; li < 4; ++li) {
        int idx = li * 256 + t;
        int row = 64 + (idx >> 6), col = idx & 63;
        int off = (row * 8 + ((col >> 3) ^ (row & 7))) * 8 + (col & 7);
        Vh[off] = (row == 64) ? (ushort)0x3F80 : (ushort)0;
        Vl[off] = 0;
    }

    f32x4 acc[5];
    #pragma unroll
    for (int nf = 0; nf < 5; ++nf) acc[nf] = (f32x4){0.f, 0.f, 0.f, 0.f};

    for (int sub = 0; sub < 7; ++sub) {
        int n0 = chunk * 448 + sub * 64;
        #pragma unroll
        for (int li = 0; li < 4; ++li) {
            int idx = li * 256 + t;
            int row = idx >> 4, sc = idx & 15;
            int off = (row * 8 + ((sc >> 1) ^ (row & 7))) * 8 + (sc & 1) * 4;
            uint4 kf = *(const uint4*)&kp[(size_t)row * N_SP + n0 + sc * 4];
            ((uint*)&Kh[off])[0] = (kf.x & 0xFFFFu) | (kf.y << 16);
            ((uint*)&Kh[off])[1] = (kf.z & 0xFFFFu) | (kf.w << 16);
            ((uint*)&Kl[off])[0] = (kf.x >> 16) | (kf.y & 0xFFFF0000u);
            ((uint*)&Kl[off])[1] = (kf.z >> 16) | (kf.w & 0xFFFF0000u);
            float4 vf = *(const float4*)&vp[(size_t)row * N_SP + n0 + sc * 4];
            ushort h0,h1,h2,h3,l0,l1,l2,l3;
            bsplit(vf.x,h0,l0); bsplit(vf.y,h1,l1); bsplit(vf.z,h2,l2); bsplit(vf.w,h3,l3);
            ((uint*)&Vh[off])[0] = (uint)h0 | ((uint)h1 << 16);
            ((uint*)&Vh[off])[1] = (uint)h2 | ((uint)h3 << 16);
            ((uint*)&Vl[off])[0] = (uint)l0 | ((uint)l1 << 16);
            ((uint*)&Vl[off])[1] = (uint)l2 | ((uint)l3 << 16);
        }
        __syncthreads();
        #pragma unroll
        for (int s = 0; s < 2; ++s) {
            int arow = wv * 16 + l15;
            int akb = (s * 4 + lg) ^ (arow & 7);
            short8 ah = *(const short8*)&Kh[(arow * 8 + akb) * 8];
            short8 al = *(const short8*)&Kl[(arow * 8 + akb) * 8];
            #pragma unroll
            for (int nf = 0; nf < 5; ++nf) {
                int brow = nf * 16 + l15;
                int bkb = (s * 4 + lg) ^ (brow & 7);
                short8 bh = *(const short8*)&Vh[(brow * 8 + bkb) * 8];
                short8 bl = *(const short8*)&Vl[(brow * 8 + bkb) * 8];
                acc[nf] = __builtin_amdgcn_mfma_f32_16x16x32_bf16(ah, bh, acc[nf], 0, 0, 0);
                acc[nf] = __builtin_amdgcn_mfma_f32_16x16x32_bf16(ah, bl, acc[nf], 0, 0, 0);
                acc[nf] = __builtin_amdgcn_mfma_f32_16x16x32_bf16(al, bh, acc[nf], 0, 0, 0);
            }
        }
        __syncthreads();
    }

    size_t base = (size_t)((b*6 + h)*7 + chunk) * 64 * 80;
    #pragma unroll
    for (int nf = 0; nf < 5; ++nf)
        #pragma unroll
        for (int r = 0; r < 4; ++r) {
            int d = wv * 16 + lg * 4 + r;
            kv_part[base + (size_t)d * 80 + nf * 16 + l15] = acc[nf][r];
        }
}

// ---------------- K2b: reduce partials -> kvT bf16 hi/lo planes [e(80)][d(64)].
__global__ __launch_bounds__(256) void k2b_reduce(
    const float* __restrict__ kv_part,
    ushort* __restrict__ kvt_h, ushort* __restrict__ kvt_l)
{
    const int bh = blockIdx.x;       // 96
    const int t = threadIdx.x;
    const float inv_n = 1.0f / (float)N_SP;
    const float* base = kv_part + (size_t)bh * 7 * 5120;
    ushort* oh = kvt_h + (size_t)bh * 5120;
    ushort* ol = kvt_l + (size_t)bh * 5120;
    float s[20];
    #pragma unroll
    for (int j = 0; j < 20; ++j) s[j] = 0.f;
    for (int c = 0; c < 7; ++c) {
        #pragma unroll
        for (int j = 0; j < 20; ++j) s[j] += base[c * 5120 + j * 256 + t];
    }
    #pragma unroll
    for (int j = 0; j < 20; ++j) {
        int i = j * 256 + t;
        int d = i / 80, e = i % 80;
        ushort h, l;
        bsplit(s[j] * inv_n, h, l);
        oh[e * 64 + d] = h;
        ol[e * 64 + d] = l;
    }
}

// ---------------- K3: 3 heads per block. Phase 1 stages x ONCE; per-head PV + conv.
#define ATT_STRIDE 68
__global__ __launch_bounds__(256, 4) void k3_attn_pe(
    const float* __restrict__ x,
    const ushort* __restrict__ wfh, const ushort* __restrict__ wfl,
    const float* __restrict__ qsc, const float* __restrict__ qsh,
    const ushort* __restrict__ kvt_h, const ushort* __restrict__ kvt_l,
    const float* __restrict__ pwsc, const float* __restrict__ psh,
    float* __restrict__ out)
{
    __shared__ __align__(16) float SBF[ATT_STRIDE * 64 + 64];   // 17.7 KB
    ushort* Bh = (ushort*)&SBF[0];     // 8 KB (aliases SBF)
    ushort* Bl = Bh + 4096;            // 8 KB

    const int bx = blockIdx.x;    // 49 n tiles
    const int hgrp = blockIdx.y;  // 2 (heads hgrp*3 .. +2)
    const int b = blockIdx.z;
    const int t = threadIdx.x;
    const int lane = t & 63, wv = t >> 6;
    const int lg = lane >> 4, l15 = lane & 15;
    const int n0 = bx * 64;

    const float* xg = x + (size_t)b * 384 * N_SP + n0;   // g=0 rows

    // ---- phase 1: q tiles for 3 heads via MFMA; x staged+split ONCE
    f32x4 qacc[3][4];
    #pragma unroll
    for (int hh = 0; hh < 3; ++hh)
        #pragma unroll
        for (int nf = 0; nf < 4; ++nf) qacc[hh][nf] = (f32x4){0.f, 0.f, 0.f, 0.f};

    for (int kt = 0; kt < 3; ++kt) {
        #pragma unroll
        for (int li = 0; li < 2; ++li) {
            int idx = li * 256 + t;
            int kp = idx >> 4;
            int nq = idx & 15;
            int k0 = kp * 2;
            const float* px = xg + (size_t)(kt * 64 + k0) * N_SP + nq * 4;
            float4 v0 = *(const float4*)px;
            float4 v1 = *(const float4*)(px + N_SP);
            ushort h0[4], l0[4], h1[4], l1[4];
            float a0[4] = {v0.x, v0.y, v0.z, v0.w};
            float a1[4] = {v1.x, v1.y, v1.z, v1.w};
            #pragma unroll
            for (int i = 0; i < 4; ++i) { bsplit(a0[i], h0[i], l0[i]); bsplit(a1[i], h1[i], l1[i]); }
            int kb = k0 >> 3, ks = kp & 3;
            #pragma unroll
            for (int i = 0; i < 4; ++i) {
                int n = nq * 4 + i;
                int chunk = n * 8 + (kb ^ FSWZ(n));
                ((uint*)Bh)[chunk * 4 + ks] = (uint)h0[i] | ((uint)h1[i] << 16);
                ((uint*)Bl)[chunk * 4 + ks] = (uint)l0[i] | ((uint)l1[i] << 16);
            }
        }
        __syncthreads();
        #pragma unroll
        for (int s = 0; s < 2; ++s) {
            int kbq = s * 4 + lg;
            int kglob = kt * 8 + kbq;
            short8 bh[4], bl[4];
            #pragma unroll
            for (int nf = 0; nf < 4; ++nf) {
                int n = nf * 16 + l15;
                int chunk = n * 8 + (kbq ^ FSWZ(n));
                bh[nf] = *(const short8*)&Bh[chunk * 8];
                bl[nf] = *(const short8*)&Bl[chunk * 8];
            }
            #pragma unroll
            for (int hh = 0; hh < 3; ++hh) {
                int rb = (hgrp * 3 + hh) * 4 + wv;   // this wave's 16 q-rows of head hh
                int off = (rb * 24 + kglob) * 128 + l15 * 8;
                short8 ah = *(const short8*)&wfh[off];
                short8 al = *(const short8*)&wfl[off];
                #pragma unroll
                for (int nf = 0; nf < 4; ++nf) {
                    qacc[hh][nf] = __builtin_amdgcn_mfma_f32_16x16x32_bf16(ah, bh[nf], qacc[hh][nf], 0, 0, 0);
                    qacc[hh][nf] = __builtin_amdgcn_mfma_f32_16x16x32_bf16(ah, bl[nf], qacc[hh][nf], 0, 0, 0);
                    qacc[hh][nf] = __builtin_amdgcn_mfma_f32_16x16x32_bf16(al, bh[nf], qacc[hh][nf], 0, 0, 0);
                }
            }
        }
        __syncthreads();
    }

    const int tx = t & 15, ty = t >> 4;
    const int p0 = n0 + tx * 4;
    const int y = p0 / 56, xc = p0 % 56;

    // ---- per-head: frag pack -> PV MFMA -> conv + BN epilogue
    #pragma unroll 1
    for (int hh = 0; hh < 3; ++hh) {
        const int h = hgrp * 3 + hh;

        // phase 2: BN + elu + bsplit -> q bf16 B-fragments into LDS
        {
            float sc4[4], sh4[4];
            #pragma unroll
            for (int r = 0; r < 4; ++r) {
                int ch = h * 64 + wv * 16 + lg * 4 + r;
                sc4[r] = qsc[ch];
                sh4[r] = qsh[ch];
            }
            int hc = wv * 4 + lg;
            #pragma unroll
            for (int nf = 0; nf < 4; ++nf) {
                ushort hhq[4], llq[4];
                #pragma unroll
                for (int r = 0; r < 4; ++r) {
                    float v = qacc[hh][nf][r] * sc4[r] + sh4[r];
                    v = v > 0.f ? v + 1.f : __expf(v);
                    bsplit(v, hhq[r], llq[r]);
                }
                int n = nf * 16 + l15;
                uint2 uh, ul;
                uh.x = (uint)hhq[0] | ((uint)hhq[1] << 16);
                uh.y = (uint)hhq[2] | ((uint)hhq[3] << 16);
                ul.x = (uint)llq[0] | ((uint)llq[1] << 16);
                ul.y = (uint)llq[2] | ((uint)llq[3] << 16);
                *(uint2*)(Bh + hc * 256 + n * 4) = uh;
                *(uint2*)(Bl + hc * 256 + n * 4) = ul;
            }
        }
        __syncthreads();

        // phase 3: B-frags to regs (this wave's n-frag = wv)
        short8 bqh[2], bql[2];
        #pragma unroll
        for (int s = 0; s < 2; ++s) {
            int hc = (s * 4 + lg) * 2;
            const ushort* ph = Bh + hc * 256 + (wv * 16 + l15) * 4;
            uint2 a0 = *(const uint2*)ph;
            uint2 a1 = *(const uint2*)(ph + 256);
            uint* pp = (uint*)&bqh[s];
            pp[0] = a0.x; pp[1] = a0.y; pp[2] = a1.x; pp[3] = a1.y;
            const ushort* pl = Bl + hc * 256 + (wv * 16 + l15) * 4;
            uint2 c0 = *(const uint2*)pl;
            uint2 c1 = *(const uint2*)(pl + 256);
            uint* qq = (uint*)&bql[s];
            qq[0] = c0.x; qq[1] = c0.y; qq[2] = c1.x; qq[3] = c1.y;
        }
        __syncthreads();   // frag reads done; SBF region reusable

        // phase 4: PV + den via MFMA (A = kvt planes, L2-hot)
        const ushort* ahb = kvt_h + (size_t)(b * 6 + h) * 5120;
        const ushort* alb = kvt_l + (size_t)(b * 6 + h) * 5120;
        f32x4 pacc[5];
        #pragma unroll
        for (int m = 0; m < 5; ++m) pacc[m] = (f32x4){0.f, 0.f, 0.f, 0.f};
        #pragma unroll
        for (int s = 0; s < 2; ++s) {
            #pragma unroll
            for (int m = 0; m < 5; ++m) {
                int off = (m * 16 + l15) * 64 + (s * 4 + lg) * 8;
                short8 ah = *(const short8*)&ahb[off];
                short8 al = *(const short8*)&alb[off];
                pacc[m] = __builtin_amdgcn_mfma_f32_16x16x32_bf16(ah, bqh[s], pacc[m], 0, 0, 0);
                pacc[m] = __builtin_amdgcn_mfma_f32_16x16x32_bf16(ah, bql[s], pacc[m], 0, 0, 0);
                pacc[m] = __builtin_amdgcn_mfma_f32_16x16x32_bf16(al, bqh[s], pacc[m], 0, 0, 0);
            }
        }
        {
            int ncol = wv * 16 + l15;
            #pragma unroll
            for (int m = 0; m < 4; ++m)
                #pragma unroll
                for (int r = 0; r < 4; ++r)
                    SBF[(m * 16 + lg * 4 + r) * ATT_STRIDE + ncol] = pacc[m][r];
            if (lg == 0)
                SBF[ATT_STRIDE * 64 + ncol] = pacc[4][0];   // den (kvt row 64 = km)
        }
        __syncthreads();

        // phase 5: conv + BN epilogue
        float den4[4];
        #pragma unroll
        for (int p = 0; p < 4; ++p) den4[p] = SBF[ATT_STRIDE * 64 + tx * 4 + p] + 1e-6f;
        #pragma unroll
        for (int j = 0; j < 4; ++j) {
            int c = h * 64 + ty * 4 + j;
            const float* xp = x + ((size_t)b * 384 + c) * N_SP;
            float s6[3][6];
            #pragma unroll
            for (int dy = 0; dy < 3; ++dy) {
                int yy = y + dy - 1;
                bool yok = (yy >= 0) && (yy < 56);
                float4 mid = make_float4(0.f, 0.f, 0.f, 0.f);
                float lf = 0.f, rt = 0.f;
                if (yok) {
                    const float* xr = xp + yy * 56;
                    mid = *(const float4*)&xr[xc];
                    if (xc > 0)  lf = xr[xc - 1];
                    if (xc < 52) rt = xr[xc + 4];
                }
                s6[dy][0] = lf;  s6[dy][1] = mid.x; s6[dy][2] = mid.y;
                s6[dy][3] = mid.z; s6[dy][4] = mid.w; s6[dy][5] = rt;
            }
            float w9[9];
            #pragma unroll
            for (int q = 0; q < 9; ++q) w9[q] = pwsc[c * 9 + q];
            float sh2 = psh[c];
            float4 r;
            float* pr = (float*)&r;
            #pragma unroll
            for (int p = 0; p < 4; ++p) {
                float conv = 0.f;
                #pragma unroll
                for (int dy = 0; dy < 3; ++dy)
                    #pragma unroll
                    for (int dx = 0; dx < 3; ++dx)
                        conv += w9[dy * 3 + dx] * s6[dy][p + dx];
                pr[p] = SBF[(ty * 4 + j) * ATT_STRIDE + tx * 4 + p] / den4[p] + conv + sh2;
            }
            *(float4*)&out[((size_t)b * 384 + c) * N_SP + p0] = r;
        }
        __syncthreads();   // SBF free before next head overwrites Bh/Bl
    }
}

extern "C" void kernel_launch(void* const* d_in, const int* in_sizes, int n_in,
                              void* d_out, int out_size, void* d_ws, size_t ws_size,
                              hipStream_t stream)
{
    const float* x        = (const float*)d_in[0];
    const float* qk_w     = (const float*)d_in[1];
    const float* qk_gamma = (const float*)d_in[2];
    const float* qk_beta  = (const float*)d_in[3];
    const float* qk_mean  = (const float*)d_in[4];
    const float* qk_var   = (const float*)d_in[5];
    const float* pe_w     = (const float*)d_in[6];
    const float* pe_gamma = (const float*)d_in[7];
    const float* pe_beta  = (const float*)d_in[8];
    const float* pe_mean  = (const float*)d_in[9];
    const float* pe_var   = (const float*)d_in[10];
    float* out = (float*)d_out;

    float* ws      = (float*)d_ws;
    uint* kq       = (uint*)ws;
    float* kv_part = ws + KVP_OFF;
    ushort* kvt_h  = (ushort*)(ws + KVT_OFF);
    ushort* kvt_l  = kvt_h + 96 * 5120;
    ushort* wfh    = (ushort*)(ws + WH_OFF);
    ushort* wfl    = wfh + WSPLIT_N;
    float* pwsc    = ws + PWS_OFF;
    float* psh     = ws + PSH_OFF;
    float* qsc     = ws + QSC_OFF;
    float* qsh     = ws + QSH_OFF;

    hipLaunchKernelGGL(p0_prep, dim3((WSPLIT_N + 255)/256), dim3(256), 0, stream,
                       qk_w, pe_w, qk_gamma, qk_beta, qk_mean, qk_var,
                       pe_gamma, pe_beta, pe_mean, pe_var,
                       wfh, wfl, pwsc, psh, qsc, qsh);
    dim3 g1(49, 2, 16);
    hipLaunchKernelGGL(k1_k_mfma, g1, dim3(256), 0, stream,
                       x, wfh, wfl, qk_gamma, qk_beta, qk_mean, qk_var, kq);
    dim3 g2(7, 6, 16);
    hipLaunchKernelGGL(k2_kv_mfma, g2, dim3(256), 0, stream, x, kq, kv_part);
    hipLaunchKernelGGL(k2b_reduce, dim3(96), dim3(256), 0, stream,
                       kv_part, kvt_h, kvt_l);
    dim3 g3(49, 2, 16);
    hipLaunchKernelGGL(k3_attn_pe, g3, dim3(256), 0, stream,
                       x, wfh, wfl, qsc, qsh, kvt_h, kvt_l, pwsc, psh, out);
}

// Round 18
// 212.509 us; speedup vs baseline: 1.2549x; 1.2549x over previous
//
#include <hip/hip_runtime.h>
#include <math.h>

#define N_SP 3136
#define BN_EPS 1e-5f

typedef __attribute__((ext_vector_type(8))) short short8;
typedef __attribute__((ext_vector_type(4))) float f32x4;

// ws layout (float elements)
#define K_SZ    (16*384*N_SP)            // kq packed u32 (k, bf16 hi|lo<<16)
#define KVP_OFF (K_SZ)
#define KVP_SZ  (16*6*7*64*80)           // per-chunk partials [d][80]
#define KVF_OFF (KVP_OFF + KVP_SZ)
#define KVF_SZ  (16*6*64*64)             // kv fp32 [bh][d][e]
#define KM_OFF  (KVF_OFF + KVF_SZ)
#define KM_SZ   (16*6*64)
#define WH_OFF  (KM_OFF + KM_SZ)         // wfrag hi/lo ushort planes
#define WSPLIT_N (2*384*192)
#define WF_G    (384*192)                // 73728 per group per plane
#define PWS_OFF (WH_OFF + WSPLIT_N)      // pwsc 384*9
#define PSH_OFF (PWS_OFF + 384*9)
#define QSC_OFF (PSH_OFF + 384)          // q BN scale (channels 0..383)
#define QSH_OFF (QSC_OFF + 384)

// both-sides LDS swizzle for B tiles
#define FSWZ(n) ((((n) >> 1) ^ ((n) >> 2)) & 7)

__device__ __forceinline__ void bsplit(float f, ushort& h, ushort& l) {
    uint u = __float_as_uint(f);
    uint hr = (u + 0x7FFFu + ((u >> 16) & 1u)) >> 16;
    h = (ushort)hr;
    float fh = __uint_as_float(hr << 16);
    float fl = f - fh;
    uint v = __float_as_uint(fl);
    l = (ushort)((v + 0x7FFFu + ((v >> 16) & 1u)) >> 16);
}

// ---------------- P0: qk_w -> fragment-layout bf16 hi/lo; pe weight/BN prescale; q BN tables.
__global__ __launch_bounds__(256) void p0_prep(
    const float* __restrict__ qk_w, const float* __restrict__ pe_w,
    const float* __restrict__ qk_gamma, const float* __restrict__ qk_beta,
    const float* __restrict__ qk_mean, const float* __restrict__ qk_var,
    const float* __restrict__ pgamma, const float* __restrict__ pbeta,
    const float* __restrict__ pmean, const float* __restrict__ pvar,
    ushort* __restrict__ wfh, ushort* __restrict__ wfl,
    float* __restrict__ pwsc, float* __restrict__ psh,
    float* __restrict__ qsc, float* __restrict__ qsh)
{
    int idx = blockIdx.x * 256 + threadIdx.x;
    if (idx < WSPLIT_N) {
        int g = (idx >= WF_G) ? 1 : 0;
        int rem = idx - g * WF_G;
        int row = rem / 192, k = rem % 192;
        ushort h, l;
        bsplit(qk_w[idx], h, l);
        int dst = g * WF_G + ((row >> 4) * 24 + (k >> 3)) * 128 + (row & 15) * 8 + (k & 7);
        wfh[dst] = h;
        wfl[dst] = l;
    }
    if (idx < 384) {
        float sc = pgamma[idx] / sqrtf(pvar[idx] + BN_EPS);
        psh[idx] = pbeta[idx] - pmean[idx] * sc;
        #pragma unroll
        for (int q = 0; q < 9; ++q) pwsc[idx * 9 + q] = pe_w[idx * 9 + q] * sc;
        float qs = qk_gamma[idx] / sqrtf(qk_var[idx] + BN_EPS);
        qsc[idx] = qs;
        qsh[idx] = qk_beta[idx] - qk_mean[idx] * qs;
    }
}

// ---------------- K1: k-only GEMM (g=1). Block = 192 rows x 64 n; A frag-direct.
__global__ __launch_bounds__(256, 4) void k1_k_mfma(
    const float* __restrict__ x, const ushort* __restrict__ wfh, const ushort* __restrict__ wfl,
    const float* __restrict__ gamma, const float* __restrict__ beta,
    const float* __restrict__ mean, const float* __restrict__ var,
    uint* __restrict__ kq)
{
    __shared__ __align__(16) ushort Bh[4096];
    __shared__ __align__(16) ushort Bl[4096];
    __shared__ float scs[192], shs[192];

    const int bx = blockIdx.x;           // 49 n-tiles
    const int by = blockIdx.y;           // 2 row-halves (192 each)
    const int b = blockIdx.z;            // 16
    const int t = threadIdx.x;
    const int lane = t & 63, wv = t >> 6;
    const int lg = lane >> 4, l15 = lane & 15;

    f32x4 acc[3][4];
    #pragma unroll
    for (int mf = 0; mf < 3; ++mf)
        #pragma unroll
        for (int nf = 0; nf < 4; ++nf)
            acc[mf][nf] = (f32x4){0.f, 0.f, 0.f, 0.f};

    const float* xg = x + (size_t)(b * 384 + 192) * N_SP + bx * 64;   // g=1 rows
    const ushort* wfbh = wfh + WF_G;
    const ushort* wfbl = wfl + WF_G;

    for (int i = t; i < 192; i += 256) {
        int ch = 384 + by * 192 + i;
        float sc = gamma[ch] / sqrtf(var[ch] + BN_EPS);
        scs[i] = sc;
        shs[i] = beta[ch] - mean[ch] * sc;
    }

    for (int kt = 0; kt < 3; ++kt) {
        #pragma unroll
        for (int li = 0; li < 2; ++li) {
            int idx = li * 256 + t;
            int kp = idx >> 4;           // 0..31 (k-row pairs)
            int nq = idx & 15;
            int k0 = kp * 2;
            const float* px = xg + (size_t)(kt * 64 + k0) * N_SP + nq * 4;
            float4 v0 = *(const float4*)px;
            float4 v1 = *(const float4*)(px + N_SP);
            ushort h0[4], l0[4], h1[4], l1[4];
            float a0[4] = {v0.x, v0.y, v0.z, v0.w};
            float a1[4] = {v1.x, v1.y, v1.z, v1.w};
            #pragma unroll
            for (int i2 = 0; i2 < 4; ++i2) { bsplit(a0[i2], h0[i2], l0[i2]); bsplit(a1[i2], h1[i2], l1[i2]); }
            int kb = k0 >> 3, ks = kp & 3;
            #pragma unroll
            for (int i2 = 0; i2 < 4; ++i2) {
                int n = nq * 4 + i2;
                int chunk = n * 8 + (kb ^ FSWZ(n));
                ((uint*)Bh)[chunk * 4 + ks] = (uint)h0[i2] | ((uint)h1[i2] << 16);
                ((uint*)Bl)[chunk * 4 + ks] = (uint)l0[i2] | ((uint)l1[i2] << 16);
            }
        }
        __syncthreads();
        #pragma unroll
        for (int s = 0; s < 2; ++s) {
            int kbq = s * 4 + lg;
            int kglob = kt * 8 + kbq;
            short8 bh[4], bl[4];
            #pragma unroll
            for (int nf = 0; nf < 4; ++nf) {
                int n = nf * 16 + l15;
                int chunk = n * 8 + (kbq ^ FSWZ(n));
                bh[nf] = *(const short8*)&Bh[chunk * 8];
                bl[nf] = *(const short8*)&Bl[chunk * 8];
            }
            #pragma unroll
            for (int mf = 0; mf < 3; ++mf) {
                int rb = by * 12 + wv * 3 + mf;
                int off = (rb * 24 + kglob) * 128 + l15 * 8;
                short8 ah = *(const short8*)&wfbh[off];
                short8 al = *(const short8*)&wfbl[off];
                #pragma unroll
                for (int nf = 0; nf < 4; ++nf) {
                    acc[mf][nf] = __builtin_amdgcn_mfma_f32_16x16x32_bf16(ah, bh[nf], acc[mf][nf], 0, 0, 0);
                    acc[mf][nf] = __builtin_amdgcn_mfma_f32_16x16x32_bf16(ah, bl[nf], acc[mf][nf], 0, 0, 0);
                    acc[mf][nf] = __builtin_amdgcn_mfma_f32_16x16x32_bf16(al, bh[nf], acc[mf][nf], 0, 0, 0);
                }
            }
        }
        __syncthreads();
    }

    size_t obase = ((size_t)b * 384 + by * 192) * N_SP + bx * 64;
    #pragma unroll
    for (int mf = 0; mf < 3; ++mf)
        #pragma unroll
        for (int nf = 0; nf < 4; ++nf) {
            #pragma unroll
            for (int r = 0; r < 4; ++r) {
                int lrow = wv * 48 + mf * 16 + lg * 4 + r;
                float v = acc[mf][nf][r] * scs[lrow] + shs[lrow];
                v = v > 0.f ? v + 1.f : __expf(v);
                ushort hh, ll;
                bsplit(v, hh, ll);
                kq[obase + (size_t)lrow * N_SP + nf * 16 + l15] = (uint)hh | ((uint)ll << 16);
            }
        }
}

// ---------------- K2: kv + ksum via MFMA; k from packed u32, v from fp32 x (unchanged).
__global__ __launch_bounds__(256) void k2_kv_mfma(
    const float* __restrict__ x, const uint* __restrict__ kq,
    float* __restrict__ kv_part)
{
    __shared__ __align__(16) ushort Kh[4096], Kl[4096];
    __shared__ __align__(16) ushort Vh[5120], Vl[5120];

    const int chunk = blockIdx.x;      // 7
    const int h = blockIdx.y, b = blockIdx.z;
    const int t = threadIdx.x;
    const int lane = t & 63, wv = t >> 6;
    const int lg = lane >> 4, l15 = lane & 15;

    const uint* kp  = kq + (size_t)(b*384 + h*64) * N_SP;
    const float* vp = x  + (size_t)(b*384 + h*64) * N_SP;

    #pragma unroll
    for (int li = 0; li < 4; ++li) {
        int idx = li * 256 + t;
        int row = 64 + (idx >> 6), col = idx & 63;
        int off = (row * 8 + ((col >> 3) ^ (row & 7))) * 8 + (col & 7);
        Vh[off] = (row == 64) ? (ushort)0x3F80 : (ushort)0;
        Vl[off] = 0;
    }

    f32x4 acc[5];
    #pragma unroll
    for (int nf = 0; nf < 5; ++nf) acc[nf] = (f32x4){0.f, 0.f, 0.f, 0.f};

    for (int sub = 0; sub < 7; ++sub) {
        int n0 = chunk * 448 + sub * 64;
        #pragma unroll
        for (int li = 0; li < 4; ++li) {
            int idx = li * 256 + t;
            int row = idx >> 4, sc = idx & 15;
            int off = (row * 8 + ((sc >> 1) ^ (row & 7))) * 8 + (sc & 1) * 4;
            uint4 kf = *(const uint4*)&kp[(size_t)row * N_SP + n0 + sc * 4];
            ((uint*)&Kh[off])[0] = (kf.x & 0xFFFFu) | (kf.y << 16);
            ((uint*)&Kh[off])[1] = (kf.z & 0xFFFFu) | (kf.w << 16);
            ((uint*)&Kl[off])[0] = (kf.x >> 16) | (kf.y & 0xFFFF0000u);
            ((uint*)&Kl[off])[1] = (kf.z >> 16) | (kf.w & 0xFFFF0000u);
            float4 vf = *(const float4*)&vp[(size_t)row * N_SP + n0 + sc * 4];
            ushort h0,h1,h2,h3,l0,l1,l2,l3;
            bsplit(vf.x,h0,l0); bsplit(vf.y,h1,l1); bsplit(vf.z,h2,l2); bsplit(vf.w,h3,l3);
            ((uint*)&Vh[off])[0] = (uint)h0 | ((uint)h1 << 16);
            ((uint*)&Vh[off])[1] = (uint)h2 | ((uint)h3 << 16);
            ((uint*)&Vl[off])[0] = (uint)l0 | ((uint)l1 << 16);
            ((uint*)&Vl[off])[1] = (uint)l2 | ((uint)l3 << 16);
        }
        __syncthreads();
        #pragma unroll
        for (int s = 0; s < 2; ++s) {
            int arow = wv * 16 + l15;
            int akb = (s * 4 + lg) ^ (arow & 7);
            short8 ah = *(const short8*)&Kh[(arow * 8 + akb) * 8];
            short8 al = *(const short8*)&Kl[(arow * 8 + akb) * 8];
            #pragma unroll
            for (int nf = 0; nf < 5; ++nf) {
                int brow = nf * 16 + l15;
                int bkb = (s * 4 + lg) ^ (brow & 7);
                short8 bh = *(const short8*)&Vh[(brow * 8 + bkb) * 8];
                short8 bl = *(const short8*)&Vl[(brow * 8 + bkb) * 8];
                acc[nf] = __builtin_amdgcn_mfma_f32_16x16x32_bf16(ah, bh, acc[nf], 0, 0, 0);
                acc[nf] = __builtin_amdgcn_mfma_f32_16x16x32_bf16(ah, bl, acc[nf], 0, 0, 0);
                acc[nf] = __builtin_amdgcn_mfma_f32_16x16x32_bf16(al, bh, acc[nf], 0, 0, 0);
            }
        }
        __syncthreads();
    }

    size_t base = (size_t)((b*6 + h)*7 + chunk) * 64 * 80;
    #pragma unroll
    for (int nf = 0; nf < 5; ++nf)
        #pragma unroll
        for (int r = 0; r < 4; ++r) {
            int d = wv * 16 + lg * 4 + r;
            kv_part[base + (size_t)d * 80 + nf * 16 + l15] = acc[nf][r];
        }
}

// ---------------- K2b: reduce partials -> kv fp32 [bh][d][e] + km fp32 [bh][d].
__global__ __launch_bounds__(256) void k2b_reduce(
    const float* __restrict__ kv_part,
    float* __restrict__ kvf, float* __restrict__ km)
{
    const int bh = blockIdx.x;       // 96
    const int t = threadIdx.x;
    const float inv_n = 1.0f / (float)N_SP;
    const float* base = kv_part + (size_t)bh * 7 * 5120;
    float s[20];
    #pragma unroll
    for (int j = 0; j < 20; ++j) s[j] = 0.f;
    for (int c = 0; c < 7; ++c) {
        #pragma unroll
        for (int j = 0; j < 20; ++j) s[j] += base[c * 5120 + j * 256 + t];
    }
    #pragma unroll
    for (int j = 0; j < 20; ++j) {
        int i = j * 256 + t;
        int d = i / 80, e = i % 80;
        float v = s[j] * inv_n;
        if (e < 64)       kvf[(size_t)bh * 4096 + d * 64 + e] = v;
        else if (e == 64) km[bh * 64 + d] = v;
    }
}

// ---------------- K3: q recomputed on the fly (MFMA) + attn dot + conv + BN.
// LDS union: staging (16 KB) aliased inside qs (17.4 KB). One q-tile per (b,h,n-tile).
__global__ __launch_bounds__(256) void k3_attn_pe(
    const float* __restrict__ x,
    const ushort* __restrict__ wfh, const ushort* __restrict__ wfl,
    const float* __restrict__ qsc, const float* __restrict__ qsh,
    const float* __restrict__ kvf, const float* __restrict__ km,
    const float* __restrict__ pwsc, const float* __restrict__ psh,
    float* __restrict__ out)
{
    __shared__ float qs[64][68];   // 17.4 KB; staging aliased below
    __shared__ float kms[64];
    ushort* Bh = (ushort*)&qs[0][0];   // 8 KB
    ushort* Bl = Bh + 4096;            // 8 KB (total 16 KB < 17.4 KB)

    const int bx = blockIdx.x;    // 49 n tiles
    const int h = blockIdx.y, b = blockIdx.z;
    const int t = threadIdx.x;
    const int lane = t & 63, wv = t >> 6;
    const int lg = lane >> 4, l15 = lane & 15;
    const int n0 = bx * 64;

    const float* xg = x + (size_t)b * 384 * N_SP + n0;   // g=0 rows (0..191)
    const ushort* wfbh = wfh;                             // g=0 W frags
    const ushort* wfbl = wfl;

    // ---- compute q tile via MFMA (identical accumulation order to old K1 g=0)
    f32x4 qacc[4];
    #pragma unroll
    for (int nf = 0; nf < 4; ++nf) qacc[nf] = (f32x4){0.f, 0.f, 0.f, 0.f};

    for (int kt = 0; kt < 3; ++kt) {
        #pragma unroll
        for (int li = 0; li < 2; ++li) {
            int idx = li * 256 + t;
            int kp = idx >> 4;
            int nq = idx & 15;
            int k0 = kp * 2;
            const float* px = xg + (size_t)(kt * 64 + k0) * N_SP + nq * 4;
            float4 v0 = *(const float4*)px;
            float4 v1 = *(const float4*)(px + N_SP);
            ushort h0[4], l0[4], h1[4], l1[4];
            float a0[4] = {v0.x, v0.y, v0.z, v0.w};
            float a1[4] = {v1.x, v1.y, v1.z, v1.w};
            #pragma unroll
            for (int i = 0; i < 4; ++i) { bsplit(a0[i], h0[i], l0[i]); bsplit(a1[i], h1[i], l1[i]); }
            int kb = k0 >> 3, ks = kp & 3;
            #pragma unroll
            for (int i = 0; i < 4; ++i) {
                int n = nq * 4 + i;
                int chunk = n * 8 + (kb ^ FSWZ(n));
                ((uint*)Bh)[chunk * 4 + ks] = (uint)h0[i] | ((uint)h1[i] << 16);
                ((uint*)Bl)[chunk * 4 + ks] = (uint)l0[i] | ((uint)l1[i] << 16);
            }
        }
        __syncthreads();
        #pragma unroll
        for (int s = 0; s < 2; ++s) {
            int kbq = s * 4 + lg;
            int kglob = kt * 8 + kbq;
            short8 bh[4], bl[4];
            #pragma unroll
            for (int nf = 0; nf < 4; ++nf) {
                int n = nf * 16 + l15;
                int chunk = n * 8 + (kbq ^ FSWZ(n));
                bh[nf] = *(const short8*)&Bh[chunk * 8];
                bl[nf] = *(const short8*)&Bl[chunk * 8];
            }
            int rb = h * 4 + wv;   // q row-block for this wave (16 d-rows)
            int off = (rb * 24 + kglob) * 128 + l15 * 8;
            short8 ah = *(const short8*)&wfbh[off];
            short8 al = *(const short8*)&wfbl[off];
            #pragma unroll
            for (int nf = 0; nf < 4; ++nf) {
                qacc[nf] = __builtin_amdgcn_mfma_f32_16x16x32_bf16(ah, bh[nf], qacc[nf], 0, 0, 0);
                qacc[nf] = __builtin_amdgcn_mfma_f32_16x16x32_bf16(ah, bl[nf], qacc[nf], 0, 0, 0);
                qacc[nf] = __builtin_amdgcn_mfma_f32_16x16x32_bf16(al, bh[nf], qacc[nf], 0, 0, 0);
            }
        }
        __syncthreads();   // last iteration: all waves done with B frags -> qs writable
    }

    // ---- BN + elu + write q tile into qs (aliases staging, safe after barrier)
    {
        float sc4[4], sh4[4];
        #pragma unroll
        for (int r = 0; r < 4; ++r) {
            int ch = h * 64 + wv * 16 + lg * 4 + r;
            sc4[r] = qsc[ch];
            sh4[r] = qsh[ch];
        }
        #pragma unroll
        for (int nf = 0; nf < 4; ++nf) {
            int col = nf * 16 + l15;
            #pragma unroll
            for (int r = 0; r < 4; ++r) {
                int row = wv * 16 + lg * 4 + r;
                float v = qacc[nf][r] * sc4[r] + sh4[r];
                v = v > 0.f ? v + 1.f : __expf(v);
                qs[row][col] = v;
            }
        }
    }
    if (t < 64) kms[t] = km[(b * 6 + h) * 64 + t];
    __syncthreads();

    // ---- attn dot + conv epilogue (measured-104us structure)
    const int tx = t & 15, ty = t >> 4;
    const float* kvp = kvf + (size_t)(b * 6 + h) * 4096;
    float acc[4][4] = {};   // [p=pixel][j=channel]
    float den[4] = {};
    #pragma unroll 8
    for (int d = 0; d < 64; ++d) {
        float4 qn = *(const float4*)&qs[d][tx * 4];
        float4 ke = *(const float4*)&kvp[d * 64 + ty * 4];
        float qq[4] = {qn.x, qn.y, qn.z, qn.w}, kk[4] = {ke.x, ke.y, ke.z, ke.w};
        float kmd = kms[d];
        #pragma unroll
        for (int p = 0; p < 4; ++p) {
            den[p] += qq[p] * kmd;
            #pragma unroll
            for (int j = 0; j < 4; ++j) acc[p][j] += qq[p] * kk[j];
        }
    }

    const int p0 = n0 + tx * 4;
    const int y = p0 / 56, xc = p0 % 56;
    #pragma unroll
    for (int j = 0; j < 4; ++j) {
        int c = h * 64 + ty * 4 + j;
        const float* xp = x + ((size_t)b * 384 + c) * N_SP;
        float s6[3][6];
        #pragma unroll
        for (int dy = 0; dy < 3; ++dy) {
            int yy = y + dy - 1;
            bool yok = (yy >= 0) && (yy < 56);
            float4 mid = make_float4(0.f, 0.f, 0.f, 0.f);
            float lf = 0.f, rt = 0.f;
            if (yok) {
                const float* xr = xp + yy * 56;
                mid = *(const float4*)&xr[xc];
                if (xc > 0)  lf = xr[xc - 1];
                if (xc < 52) rt = xr[xc + 4];
            }
            s6[dy][0] = lf;  s6[dy][1] = mid.x; s6[dy][2] = mid.y;
            s6[dy][3] = mid.z; s6[dy][4] = mid.w; s6[dy][5] = rt;
        }
        float w9[9];
        #pragma unroll
        for (int q = 0; q < 9; ++q) w9[q] = pwsc[c * 9 + q];
        float sh2 = psh[c];
        float4 r;
        float* pr = (float*)&r;
        #pragma unroll
        for (int p = 0; p < 4; ++p) {
            float conv = 0.f;
            #pragma unroll
            for (int dy = 0; dy < 3; ++dy)
                #pragma unroll
                for (int dx = 0; dx < 3; ++dx)
                    conv += w9[dy * 3 + dx] * s6[dy][p + dx];
            pr[p] = acc[p][j] / (den[p] + 1e-6f) + conv + sh2;
        }
        *(float4*)&out[((size_t)b * 384 + c) * N_SP + p0] = r;
    }
}

extern "C" void kernel_launch(void* const* d_in, const int* in_sizes, int n_in,
                              void* d_out, int out_size, void* d_ws, size_t ws_size,
                              hipStream_t stream)
{
    const float* x        = (const float*)d_in[0];
    const float* qk_w     = (const float*)d_in[1];
    const float* qk_gamma = (const float*)d_in[2];
    const float* qk_beta  = (const float*)d_in[3];
    const float* qk_mean  = (const float*)d_in[4];
    const float* qk_var   = (const float*)d_in[5];
    const float* pe_w     = (const float*)d_in[6];
    const float* pe_gamma = (const float*)d_in[7];
    const float* pe_beta  = (const float*)d_in[8];
    const float* pe_mean  = (const float*)d_in[9];
    const float* pe_var   = (const float*)d_in[10];
    float* out = (float*)d_out;

    float* ws      = (float*)d_ws;
    uint* kq       = (uint*)ws;
    float* kv_part = ws + KVP_OFF;
    float* kvf     = ws + KVF_OFF;
    float* km      = ws + KM_OFF;
    ushort* wfh    = (ushort*)(ws + WH_OFF);
    ushort* wfl    = wfh + WSPLIT_N;
    float* pwsc    = ws + PWS_OFF;
    float* psh     = ws + PSH_OFF;
    float* qsc     = ws + QSC_OFF;
    float* qsh     = ws + QSH_OFF;

    hipLaunchKernelGGL(p0_prep, dim3((WSPLIT_N + 255)/256), dim3(256), 0, stream,
                       qk_w, pe_w, qk_gamma, qk_beta, qk_mean, qk_var,
                       pe_gamma, pe_beta, pe_mean, pe_var,
                       wfh, wfl, pwsc, psh, qsc, qsh);
    dim3 g1(49, 2, 16);
    hipLaunchKernelGGL(k1_k_mfma, g1, dim3(256), 0, stream,
                       x, wfh, wfl, qk_gamma, qk_beta, qk_mean, qk_var, kq);
    dim3 g2(7, 6, 16);
    hipLaunchKernelGGL(k2_kv_mfma, g2, dim3(256), 0, stream, x, kq, kv_part);
    hipLaunchKernelGGL(k2b_reduce, dim3(96), dim3(256), 0, stream,
                       kv_part, kvf, km);
    dim3 g3(49, 6, 16);
    hipLaunchKernelGGL(k3_attn_pe, g3, dim3(256), 0, stream,
                       x, wfh, wfl, qsc, qsh, kvf, km, pwsc, psh, out);
}

// Round 19
// 202.058 us; speedup vs baseline: 1.3198x; 1.0517x over previous
//
#include <hip/hip_runtime.h>
#include <math.h>

#define N_SP 3136
#define BN_EPS 1e-5f

typedef __attribute__((ext_vector_type(8))) short short8;
typedef __attribute__((ext_vector_type(4))) float f32x4;

// ws layout (float elements)
#define K_SZ    (16*384*N_SP)            // kq packed u32 (k, bf16 hi|lo<<16)
#define KVP_OFF (K_SZ)
#define KVP_SZ  (16*6*7*64*80)           // per-chunk partials [d][80]
#define KVF_OFF (KVP_OFF + KVP_SZ)
#define KVF_SZ  (16*6*64*64)             // kv fp32 [bh][d][e]
#define KM_OFF  (KVF_OFF + KVF_SZ)
#define KM_SZ   (16*6*64)
#define WH_OFF  (KM_OFF + KM_SZ)         // wfrag hi/lo ushort planes
#define WSPLIT_N (2*384*192)
#define WF_G    (384*192)                // 73728 per group per plane
#define PWS_OFF (WH_OFF + WSPLIT_N)      // pwsc 384*9
#define PSH_OFF (PWS_OFF + 384*9)
#define QSC_OFF (PSH_OFF + 384)          // q BN scale (channels 0..383)
#define QSH_OFF (QSC_OFF + 384)

// both-sides LDS swizzle for B tiles
#define FSWZ(n) ((((n) >> 1) ^ ((n) >> 2)) & 7)

__device__ __forceinline__ void bsplit(float f, ushort& h, ushort& l) {
    uint u = __float_as_uint(f);
    uint hr = (u + 0x7FFFu + ((u >> 16) & 1u)) >> 16;
    h = (ushort)hr;
    float fh = __uint_as_float(hr << 16);
    float fl = f - fh;
    uint v = __float_as_uint(fl);
    l = (ushort)((v + 0x7FFFu + ((v >> 16) & 1u)) >> 16);
}

// ---------------- P0: qk_w -> fragment-layout bf16 hi/lo; pe weight/BN prescale; q BN tables.
__global__ __launch_bounds__(256) void p0_prep(
    const float* __restrict__ qk_w, const float* __restrict__ pe_w,
    const float* __restrict__ qk_gamma, const float* __restrict__ qk_beta,
    const float* __restrict__ qk_mean, const float* __restrict__ qk_var,
    const float* __restrict__ pgamma, const float* __restrict__ pbeta,
    const float* __restrict__ pmean, const float* __restrict__ pvar,
    ushort* __restrict__ wfh, ushort* __restrict__ wfl,
    float* __restrict__ pwsc, float* __restrict__ psh,
    float* __restrict__ qsc, float* __restrict__ qsh)
{
    int idx = blockIdx.x * 256 + threadIdx.x;
    if (idx < WSPLIT_N) {
        int g = (idx >= WF_G) ? 1 : 0;
        int rem = idx - g * WF_G;
        int row = rem / 192, k = rem % 192;
        ushort h, l;
        bsplit(qk_w[idx], h, l);
        int dst = g * WF_G + ((row >> 4) * 24 + (k >> 3)) * 128 + (row & 15) * 8 + (k & 7);
        wfh[dst] = h;
        wfl[dst] = l;
    }
    if (idx < 384) {
        float sc = pgamma[idx] / sqrtf(pvar[idx] + BN_EPS);
        psh[idx] = pbeta[idx] - pmean[idx] * sc;
        #pragma unroll
        for (int q = 0; q < 9; ++q) pwsc[idx * 9 + q] = pe_w[idx * 9 + q] * sc;
        float qs = qk_gamma[idx] / sqrtf(qk_var[idx] + BN_EPS);
        qsc[idx] = qs;
        qsh[idx] = qk_beta[idx] - qk_mean[idx] * qs;
    }
}

// ---------------- K1: k-only GEMM (g=1). Block = 192 rows x 64 n; A frag-direct.
__global__ __launch_bounds__(256, 4) void k1_k_mfma(
    const float* __restrict__ x, const ushort* __restrict__ wfh, const ushort* __restrict__ wfl,
    const float* __restrict__ gamma, const float* __restrict__ beta,
    const float* __restrict__ mean, const float* __restrict__ var,
    uint* __restrict__ kq)
{
    __shared__ __align__(16) ushort Bh[4096];
    __shared__ __align__(16) ushort Bl[4096];
    __shared__ float scs[192], shs[192];

    const int bx = blockIdx.x;           // 49 n-tiles
    const int by = blockIdx.y;           // 2 row-halves (192 each)
    const int b = blockIdx.z;            // 16
    const int t = threadIdx.x;
    const int lane = t & 63, wv = t >> 6;
    const int lg = lane >> 4, l15 = lane & 15;

    f32x4 acc[3][4];
    #pragma unroll
    for (int mf = 0; mf < 3; ++mf)
        #pragma unroll
        for (int nf = 0; nf < 4; ++nf)
            acc[mf][nf] = (f32x4){0.f, 0.f, 0.f, 0.f};

    const float* xg = x + (size_t)(b * 384 + 192) * N_SP + bx * 64;   // g=1 rows
    const ushort* wfbh = wfh + WF_G;
    const ushort* wfbl = wfl + WF_G;

    for (int i = t; i < 192; i += 256) {
        int ch = 384 + by * 192 + i;
        float sc = gamma[ch] / sqrtf(var[ch] + BN_EPS);
        scs[i] = sc;
        shs[i] = beta[ch] - mean[ch] * sc;
    }

    for (int kt = 0; kt < 3; ++kt) {
        #pragma unroll
        for (int li = 0; li < 2; ++li) {
            int idx = li * 256 + t;
            int kp = idx >> 4;           // 0..31 (k-row pairs)
            int nq = idx & 15;
            int k0 = kp * 2;
            const float* px = xg + (size_t)(kt * 64 + k0) * N_SP + nq * 4;
            float4 v0 = *(const float4*)px;
            float4 v1 = *(const float4*)(px + N_SP);
            ushort h0[4], l0[4], h1[4], l1[4];
            float a0[4] = {v0.x, v0.y, v0.z, v0.w};
            float a1[4] = {v1.x, v1.y, v1.z, v1.w};
            #pragma unroll
            for (int i2 = 0; i2 < 4; ++i2) { bsplit(a0[i2], h0[i2], l0[i2]); bsplit(a1[i2], h1[i2], l1[i2]); }
            int kb = k0 >> 3, ks = kp & 3;
            #pragma unroll
            for (int i2 = 0; i2 < 4; ++i2) {
                int n = nq * 4 + i2;
                int chunk = n * 8 + (kb ^ FSWZ(n));
                ((uint*)Bh)[chunk * 4 + ks] = (uint)h0[i2] | ((uint)h1[i2] << 16);
                ((uint*)Bl)[chunk * 4 + ks] = (uint)l0[i2] | ((uint)l1[i2] << 16);
            }
        }
        __syncthreads();
        #pragma unroll
        for (int s = 0; s < 2; ++s) {
            int kbq = s * 4 + lg;
            int kglob = kt * 8 + kbq;
            short8 bh[4], bl[4];
            #pragma unroll
            for (int nf = 0; nf < 4; ++nf) {
                int n = nf * 16 + l15;
                int chunk = n * 8 + (kbq ^ FSWZ(n));
                bh[nf] = *(const short8*)&Bh[chunk * 8];
                bl[nf] = *(const short8*)&Bl[chunk * 8];
            }
            #pragma unroll
            for (int mf = 0; mf < 3; ++mf) {
                int rb = by * 12 + wv * 3 + mf;
                int off = (rb * 24 + kglob) * 128 + l15 * 8;
                short8 ah = *(const short8*)&wfbh[off];
                short8 al = *(const short8*)&wfbl[off];
                #pragma unroll
                for (int nf = 0; nf < 4; ++nf) {
                    acc[mf][nf] = __builtin_amdgcn_mfma_f32_16x16x32_bf16(ah, bh[nf], acc[mf][nf], 0, 0, 0);
                    acc[mf][nf] = __builtin_amdgcn_mfma_f32_16x16x32_bf16(ah, bl[nf], acc[mf][nf], 0, 0, 0);
                    acc[mf][nf] = __builtin_amdgcn_mfma_f32_16x16x32_bf16(al, bh[nf], acc[mf][nf], 0, 0, 0);
                }
            }
        }
        __syncthreads();
    }

    size_t obase = ((size_t)b * 384 + by * 192) * N_SP + bx * 64;
    #pragma unroll
    for (int mf = 0; mf < 3; ++mf)
        #pragma unroll
        for (int nf = 0; nf < 4; ++nf) {
            #pragma unroll
            for (int r = 0; r < 4; ++r) {
                int lrow = wv * 48 + mf * 16 + lg * 4 + r;
                float v = acc[mf][nf][r] * scs[lrow] + shs[lrow];
                v = v > 0.f ? v + 1.f : __expf(v);
                ushort hh, ll;
                bsplit(v, hh, ll);
                kq[obase + (size_t)lrow * N_SP + nf * 16 + l15] = (uint)hh | ((uint)ll << 16);
            }
        }
}

// ---------------- K2: kv + ksum via MFMA; k from packed u32, v from fp32 x (unchanged).
__global__ __launch_bounds__(256) void k2_kv_mfma(
    const float* __restrict__ x, const uint* __restrict__ kq,
    float* __restrict__ kv_part)
{
    __shared__ __align__(16) ushort Kh[4096], Kl[4096];
    __shared__ __align__(16) ushort Vh[5120], Vl[5120];

    const int chunk = blockIdx.x;      // 7
    const int h = blockIdx.y, b = blockIdx.z;
    const int t = threadIdx.x;
    const int lane = t & 63, wv = t >> 6;
    const int lg = lane >> 4, l15 = lane & 15;

    const uint* kp  = kq + (size_t)(b*384 + h*64) * N_SP;
    const float* vp = x  + (size_t)(b*384 + h*64) * N_SP;

    #pragma unroll
    for (int li = 0; li < 4; ++li) {
        int idx = li * 256 + t;
        int row = 64 + (idx >> 6), col = idx & 63;
        int off = (row * 8 + ((col >> 3) ^ (row & 7))) * 8 + (col & 7);
        Vh[off] = (row == 64) ? (ushort)0x3F80 : (ushort)0;
        Vl[off] = 0;
    }

    f32x4 acc[5];
    #pragma unroll
    for (int nf = 0; nf < 5; ++nf) acc[nf] = (f32x4){0.f, 0.f, 0.f, 0.f};

    for (int sub = 0; sub < 7; ++sub) {
        int n0 = chunk * 448 + sub * 64;
        #pragma unroll
        for (int li = 0; li < 4; ++li) {
            int idx = li * 256 + t;
            int row = idx >> 4, sc = idx & 15;
            int off = (row * 8 + ((sc >> 1) ^ (row & 7))) * 8 + (sc & 1) * 4;
            uint4 kf = *(const uint4*)&kp[(size_t)row * N_SP + n0 + sc * 4];
            ((uint*)&Kh[off])[0] = (kf.x & 0xFFFFu) | (kf.y << 16);
            ((uint*)&Kh[off])[1] = (kf.z & 0xFFFFu) | (kf.w << 16);
            ((uint*)&Kl[off])[0] = (kf.x >> 16) | (kf.y & 0xFFFF0000u);
            ((uint*)&Kl[off])[1] = (kf.z >> 16) | (kf.w & 0xFFFF0000u);
            float4 vf = *(const float4*)&vp[(size_t)row * N_SP + n0 + sc * 4];
            ushort h0,h1,h2,h3,l0,l1,l2,l3;
            bsplit(vf.x,h0,l0); bsplit(vf.y,h1,l1); bsplit(vf.z,h2,l2); bsplit(vf.w,h3,l3);
            ((uint*)&Vh[off])[0] = (uint)h0 | ((uint)h1 << 16);
            ((uint*)&Vh[off])[1] = (uint)h2 | ((uint)h3 << 16);
            ((uint*)&Vl[off])[0] = (uint)l0 | ((uint)l1 << 16);
            ((uint*)&Vl[off])[1] = (uint)l2 | ((uint)l3 << 16);
        }
        __syncthreads();
        #pragma unroll
        for (int s = 0; s < 2; ++s) {
            int arow = wv * 16 + l15;
            int akb = (s * 4 + lg) ^ (arow & 7);
            short8 ah = *(const short8*)&Kh[(arow * 8 + akb) * 8];
            short8 al = *(const short8*)&Kl[(arow * 8 + akb) * 8];
            #pragma unroll
            for (int nf = 0; nf < 5; ++nf) {
                int brow = nf * 16 + l15;
                int bkb = (s * 4 + lg) ^ (brow & 7);
                short8 bh = *(const short8*)&Vh[(brow * 8 + bkb) * 8];
                short8 bl = *(const short8*)&Vl[(brow * 8 + bkb) * 8];
                acc[nf] = __builtin_amdgcn_mfma_f32_16x16x32_bf16(ah, bh, acc[nf], 0, 0, 0);
                acc[nf] = __builtin_amdgcn_mfma_f32_16x16x32_bf16(ah, bl, acc[nf], 0, 0, 0);
                acc[nf] = __builtin_amdgcn_mfma_f32_16x16x32_bf16(al, bh, acc[nf], 0, 0, 0);
            }
        }
        __syncthreads();
    }

    size_t base = (size_t)((b*6 + h)*7 + chunk) * 64 * 80;
    #pragma unroll
    for (int nf = 0; nf < 5; ++nf)
        #pragma unroll
        for (int r = 0; r < 4; ++r) {
            int d = wv * 16 + lg * 4 + r;
            kv_part[base + (size_t)d * 80 + nf * 16 + l15] = acc[nf][r];
        }
}

// ---------------- K2b: reduce partials -> kv fp32 [bh][d][e] + km fp32 [bh][d].
__global__ __launch_bounds__(256) void k2b_reduce(
    const float* __restrict__ kv_part,
    float* __restrict__ kvf, float* __restrict__ km)
{
    const int bh = blockIdx.x;       // 96
    const int t = threadIdx.x;
    const float inv_n = 1.0f / (float)N_SP;
    const float* base = kv_part + (size_t)bh * 7 * 5120;
    float s[20];
    #pragma unroll
    for (int j = 0; j < 20; ++j) s[j] = 0.f;
    for (int c = 0; c < 7; ++c) {
        #pragma unroll
        for (int j = 0; j < 20; ++j) s[j] += base[c * 5120 + j * 256 + t];
    }
    #pragma unroll
    for (int j = 0; j < 20; ++j) {
        int i = j * 256 + t;
        int d = i / 80, e = i % 80;
        float v = s[j] * inv_n;
        if (e < 64)       kvf[(size_t)bh * 4096 + d * 64 + e] = v;
        else if (e == 64) km[bh * 64 + d] = v;
    }
}

// ---------------- K3: q recomputed on the fly (MFMA) + attn dot + conv + BN.
// Grid (h=6 FASTEST, bx=49, b=16): the 6 head-blocks sharing an x-tile are
// dispatch-adjacent -> L2/L3-hot staging re-reads (FETCH 233 -> ~120 MB expected).
__global__ __launch_bounds__(256) void k3_attn_pe(
    const float* __restrict__ x,
    const ushort* __restrict__ wfh, const ushort* __restrict__ wfl,
    const float* __restrict__ qsc, const float* __restrict__ qsh,
    const float* __restrict__ kvf, const float* __restrict__ km,
    const float* __restrict__ pwsc, const float* __restrict__ psh,
    float* __restrict__ out)
{
    __shared__ float qs[64][68];   // 17.4 KB; staging aliased below
    __shared__ float kms[64];
    ushort* Bh = (ushort*)&qs[0][0];   // 8 KB
    ushort* Bl = Bh + 4096;            // 8 KB (total 16 KB < 17.4 KB)

    const int h = blockIdx.x;     // 6 heads (fastest)
    const int bx = blockIdx.y;    // 49 n tiles
    const int b = blockIdx.z;
    const int t = threadIdx.x;
    const int lane = t & 63, wv = t >> 6;
    const int lg = lane >> 4, l15 = lane & 15;
    const int n0 = bx * 64;

    const float* xg = x + (size_t)b * 384 * N_SP + n0;   // g=0 rows (0..191)
    const ushort* wfbh = wfh;                             // g=0 W frags
    const ushort* wfbl = wfl;

    // ---- compute q tile via MFMA (identical accumulation order to proven path)
    f32x4 qacc[4];
    #pragma unroll
    for (int nf = 0; nf < 4; ++nf) qacc[nf] = (f32x4){0.f, 0.f, 0.f, 0.f};

    for (int kt = 0; kt < 3; ++kt) {
        #pragma unroll
        for (int li = 0; li < 2; ++li) {
            int idx = li * 256 + t;
            int kp = idx >> 4;
            int nq = idx & 15;
            int k0 = kp * 2;
            const float* px = xg + (size_t)(kt * 64 + k0) * N_SP + nq * 4;
            float4 v0 = *(const float4*)px;
            float4 v1 = *(const float4*)(px + N_SP);
            ushort h0[4], l0[4], h1[4], l1[4];
            float a0[4] = {v0.x, v0.y, v0.z, v0.w};
            float a1[4] = {v1.x, v1.y, v1.z, v1.w};
            #pragma unroll
            for (int i = 0; i < 4; ++i) { bsplit(a0[i], h0[i], l0[i]); bsplit(a1[i], h1[i], l1[i]); }
            int kb = k0 >> 3, ks = kp & 3;
            #pragma unroll
            for (int i = 0; i < 4; ++i) {
                int n = nq * 4 + i;
                int chunk = n * 8 + (kb ^ FSWZ(n));
                ((uint*)Bh)[chunk * 4 + ks] = (uint)h0[i] | ((uint)h1[i] << 16);
                ((uint*)Bl)[chunk * 4 + ks] = (uint)l0[i] | ((uint)l1[i] << 16);
            }
        }
        __syncthreads();
        #pragma unroll
        for (int s = 0; s < 2; ++s) {
            int kbq = s * 4 + lg;
            int kglob = kt * 8 + kbq;
            short8 bh[4], bl[4];
            #pragma unroll
            for (int nf = 0; nf < 4; ++nf) {
                int n = nf * 16 + l15;
                int chunk = n * 8 + (kbq ^ FSWZ(n));
                bh[nf] = *(const short8*)&Bh[chunk * 8];
                bl[nf] = *(const short8*)&Bl[chunk * 8];
            }
            int rb = h * 4 + wv;   // q row-block for this wave (16 d-rows)
            int off = (rb * 24 + kglob) * 128 + l15 * 8;
            short8 ah = *(const short8*)&wfbh[off];
            short8 al = *(const short8*)&wfbl[off];
            #pragma unroll
            for (int nf = 0; nf < 4; ++nf) {
                qacc[nf] = __builtin_amdgcn_mfma_f32_16x16x32_bf16(ah, bh[nf], qacc[nf], 0, 0, 0);
                qacc[nf] = __builtin_amdgcn_mfma_f32_16x16x32_bf16(ah, bl[nf], qacc[nf], 0, 0, 0);
                qacc[nf] = __builtin_amdgcn_mfma_f32_16x16x32_bf16(al, bh[nf], qacc[nf], 0, 0, 0);
            }
        }
        __syncthreads();   // last iteration: all waves done with B frags -> qs writable
    }

    // ---- BN + elu + write q tile into qs (aliases staging, safe after barrier)
    {
        float sc4[4], sh4[4];
        #pragma unroll
        for (int r = 0; r < 4; ++r) {
            int ch = h * 64 + wv * 16 + lg * 4 + r;
            sc4[r] = qsc[ch];
            sh4[r] = qsh[ch];
        }
        #pragma unroll
        for (int nf = 0; nf < 4; ++nf) {
            int col = nf * 16 + l15;
            #pragma unroll
            for (int r = 0; r < 4; ++r) {
                int row = wv * 16 + lg * 4 + r;
                float v = qacc[nf][r] * sc4[r] + sh4[r];
                v = v > 0.f ? v + 1.f : __expf(v);
                qs[row][col] = v;
            }
        }
    }
    if (t < 64) kms[t] = km[(b * 6 + h) * 64 + t];
    __syncthreads();

    // ---- attn dot + conv epilogue (measured-104us structure)
    const int tx = t & 15, ty = t >> 4;
    const float* kvp = kvf + (size_t)(b * 6 + h) * 4096;
    float acc[4][4] = {};   // [p=pixel][j=channel]
    float den[4] = {};
    #pragma unroll 8
    for (int d = 0; d < 64; ++d) {
        float4 qn = *(const float4*)&qs[d][tx * 4];
        float4 ke = *(const float4*)&kvp[d * 64 + ty * 4];
        float qq[4] = {qn.x, qn.y, qn.z, qn.w}, kk[4] = {ke.x, ke.y, ke.z, ke.w};
        float kmd = kms[d];
        #pragma unroll
        for (int p = 0; p < 4; ++p) {
            den[p] += qq[p] * kmd;
            #pragma unroll
            for (int j = 0; j < 4; ++j) acc[p][j] += qq[p] * kk[j];
        }
    }

    const int p0 = n0 + tx * 4;
    const int y = p0 / 56, xc = p0 % 56;
    #pragma unroll
    for (int j = 0; j < 4; ++j) {
        int c = h * 64 + ty * 4 + j;
        const float* xp = x + ((size_t)b * 384 + c) * N_SP;
        float s6[3][6];
        #pragma unroll
        for (int dy = 0; dy < 3; ++dy) {
            int yy = y + dy - 1;
            bool yok = (yy >= 0) && (yy < 56);
            float4 mid = make_float4(0.f, 0.f, 0.f, 0.f);
            float lf = 0.f, rt = 0.f;
            if (yok) {
                const float* xr = xp + yy * 56;
                mid = *(const float4*)&xr[xc];
                if (xc > 0)  lf = xr[xc - 1];
                if (xc < 52) rt = xr[xc + 4];
            }
            s6[dy][0] = lf;  s6[dy][1] = mid.x; s6[dy][2] = mid.y;
            s6[dy][3] = mid.z; s6[dy][4] = mid.w; s6[dy][5] = rt;
        }
        float w9[9];
        #pragma unroll
        for (int q = 0; q < 9; ++q) w9[q] = pwsc[c * 9 + q];
        float sh2 = psh[c];
        float4 r;
        float* pr = (float*)&r;
        #pragma unroll
        for (int p = 0; p < 4; ++p) {
            float conv = 0.f;
            #pragma unroll
            for (int dy = 0; dy < 3; ++dy)
                #pragma unroll
                for (int dx = 0; dx < 3; ++dx)
                    conv += w9[dy * 3 + dx] * s6[dy][p + dx];
            pr[p] = acc[p][j] / (den[p] + 1e-6f) + conv + sh2;
        }
        *(float4*)&out[((size_t)b * 384 + c) * N_SP + p0] = r;
    }
}

extern "C" void kernel_launch(void* const* d_in, const int* in_sizes, int n_in,
                              void* d_out, int out_size, void* d_ws, size_t ws_size,
                              hipStream_t stream)
{
    const float* x        = (const float*)d_in[0];
    const float* qk_w     = (const float*)d_in[1];
    const float* qk_gamma = (const float*)d_in[2];
    const float* qk_beta  = (const float*)d_in[3];
    const float* qk_mean  = (const float*)d_in[4];
    const float* qk_var   = (const float*)d_in[5];
    const float* pe_w     = (const float*)d_in[6];
    const float* pe_gamma = (const float*)d_in[7];
    const float* pe_beta  = (const float*)d_in[8];
    const float* pe_mean  = (const float*)d_in[9];
    const float* pe_var   = (const float*)d_in[10];
    float* out = (float*)d_out;

    float* ws      = (float*)d_ws;
    uint* kq       = (uint*)ws;
    float* kv_part = ws + KVP_OFF;
    float* kvf     = ws + KVF_OFF;
    float* km      = ws + KM_OFF;
    ushort* wfh    = (ushort*)(ws + WH_OFF);
    ushort* wfl    = wfh + WSPLIT_N;
    float* pwsc    = ws + PWS_OFF;
    float* psh     = ws + PSH_OFF;
    float* qsc     = ws + QSC_OFF;
    float* qsh     = ws + QSH_OFF;

    hipLaunchKernelGGL(p0_prep, dim3((WSPLIT_N + 255)/256), dim3(256), 0, stream,
                       qk_w, pe_w, qk_gamma, qk_beta, qk_mean, qk_var,
                       pe_gamma, pe_beta, pe_mean, pe_var,
                       wfh, wfl, pwsc, psh, qsc, qsh);
    dim3 g1(49, 2, 16);
    hipLaunchKernelGGL(k1_k_mfma, g1, dim3(256), 0, stream,
                       x, wfh, wfl, qk_gamma, qk_beta, qk_mean, qk_var, kq);
    dim3 g2(7, 6, 16);
    hipLaunchKernelGGL(k2_kv_mfma, g2, dim3(256), 0, stream, x, kq, kv_part);
    hipLaunchKernelGGL(k2b_reduce, dim3(96), dim3(256), 0, stream,
                       kv_part, kvf, km);
    dim3 g3(6, 49, 16);   // h fastest: 6 blocks sharing an x-tile are dispatch-adjacent
    hipLaunchKernelGGL(k3_attn_pe, g3, dim3(256), 0, stream,
                       x, wfh, wfl, qsc, qsh, kvf, km, pwsc, psh, out);
}